// Round 1
// baseline (285.157 us; speedup 1.0000x reference)
//
#include <hip/hip_runtime.h>

constexpr int D = 64;

// Zero the output accumulator (harness poisons d_out with 0xAA; segment_sum
// of empty segments must read 0).
__global__ void zero_out_kernel(float* __restrict__ out, int n4) {
    int i = blockIdx.x * blockDim.x + threadIdx.x;
    if (i < n4) reinterpret_cast<float4*>(out)[i] = float4{0.f, 0.f, 0.f, 0.f};
}

// One block (256 threads = 4 waves) per edge.
// Thread t loads float4 #t of the 16KB bond tile (fully coalesced: each wave
// reads a contiguous 1KB run). Row r = p*16 + t/16, chunk c = t&15.
// Partial dot (float4 . sent-chunk) reduced over the 16-lane group via
// __shfl_xor; group leader atomically accumulates into out[recv][r].
__global__ __launch_bounds__(256) void msg_kernel(
    const float* __restrict__ atom,
    const float* __restrict__ bond,
    const int*   __restrict__ conn,
    float*       __restrict__ out)
{
    const int e = blockIdx.x;
    const int t = threadIdx.x;      // 0..255
    const int c = t & 15;           // float4-chunk within a row

    const int recv = conn[2 * e + 0];
    const int send = conn[2 * e + 1];

    // sent-vector chunk this thread needs: sent[4c .. 4c+4). Broadcast across
    // the 16 threads sharing c; atom_matrix is 5 MB -> L2-resident.
    const float4 s = *reinterpret_cast<const float4*>(atom + (size_t)send * D + c * 4);

    const float4* bp = reinterpret_cast<const float4*>(bond + (size_t)e * D * D);

    #pragma unroll
    for (int p = 0; p < 4; ++p) {
        // float4 index p*256 + t -> byte offset *16 -> row (p*256+t)/16 = p*16 + t/16
        float4 b = bp[p * 256 + t];
        float v = b.x * s.x + b.y * s.y + b.z * s.z + b.w * s.w;
        // reduce across the 16 lanes that share this row (lanes l, same l>>4)
        v += __shfl_xor(v, 1);
        v += __shfl_xor(v, 2);
        v += __shfl_xor(v, 4);
        v += __shfl_xor(v, 8);
        if (c == 0) {
            const int r = p * 16 + (t >> 4);
            atomicAdd(out + (size_t)recv * D + r, v);
        }
    }
}

extern "C" void kernel_launch(void* const* d_in, const int* in_sizes, int n_in,
                              void* d_out, int out_size, void* d_ws, size_t ws_size,
                              hipStream_t stream) {
    const float* atom = (const float*)d_in[0];   // (N_ATOMS, 64) f32
    const float* bond = (const float*)d_in[1];   // (N_EDGES, 64, 64) f32
    const int*   conn = (const int*)d_in[2];     // (N_EDGES, 2) i32 [recv, send]
    float* out = (float*)d_out;                  // (N_ATOMS, 64) f32

    const int edges = in_sizes[2] / 2;
    const int n4 = out_size / 4;                 // out_size divisible by 4 (D=64)

    zero_out_kernel<<<(n4 + 255) / 256, 256, 0, stream>>>(out, n4);
    msg_kernel<<<edges, 256, 0, stream>>>(atom, bond, conn, out);
}

// Round 2
// 266.011 us; speedup vs baseline: 1.0720x; 1.0720x over previous
//
#include <hip/hip_runtime.h>

constexpr int D = 64;

typedef float v4f __attribute__((ext_vector_type(4)));

// Zero the output accumulator (harness poisons d_out with 0xAA; segment_sum
// of empty segments must read 0).
__global__ void zero_out_kernel(float* __restrict__ out, int n4) {
    int i = blockIdx.x * blockDim.x + threadIdx.x;
    if (i < n4) reinterpret_cast<float4*>(out)[i] = float4{0.f, 0.f, 0.f, 0.f};
}

// One block (256 threads = 4 waves) per edge.
// Thread t loads float4 #t of the 16KB bond tile (fully coalesced: each wave
// reads a contiguous 1KB run). Row r = p*16 + t/16, chunk c = t&15.
// bond is stream-once (1.6 GB) -> non-temporal loads keep it out of L2 so
// atom_matrix (5 MB, ~5x reuse via send idx) stays cache-resident.
// Partial dot (float4 . sent-chunk) reduced over the 16-lane group via
// __shfl_xor; group leader atomically accumulates into out[recv][r].
__global__ __launch_bounds__(256) void msg_kernel(
    const float* __restrict__ atom,
    const float* __restrict__ bond,
    const int*   __restrict__ conn,
    float*       __restrict__ out)
{
    const int e = blockIdx.x;
    const int t = threadIdx.x;      // 0..255
    const int c = t & 15;           // float4-chunk within a row

    const int recv = conn[2 * e + 0];
    const int send = conn[2 * e + 1];

    const v4f* bp = reinterpret_cast<const v4f*>(bond) + (size_t)e * 1024;

    // Issue all 4 streaming loads up front (4 VMEM in flight per thread).
    v4f b0 = __builtin_nontemporal_load(bp + 0 * 256 + t);
    v4f b1 = __builtin_nontemporal_load(bp + 1 * 256 + t);
    v4f b2 = __builtin_nontemporal_load(bp + 2 * 256 + t);
    v4f b3 = __builtin_nontemporal_load(bp + 3 * 256 + t);

    // sent-vector chunk this thread needs: sent[4c .. 4c+4). Broadcast across
    // the 16 threads sharing c; atom_matrix is 5 MB -> L2-resident.
    const v4f s = *(reinterpret_cast<const v4f*>(atom + (size_t)send * D) + c);

    float v0 = b0.x * s.x + b0.y * s.y + b0.z * s.z + b0.w * s.w;
    float v1 = b1.x * s.x + b1.y * s.y + b1.z * s.z + b1.w * s.w;
    float v2 = b2.x * s.x + b2.y * s.y + b2.z * s.z + b2.w * s.w;
    float v3 = b3.x * s.x + b3.y * s.y + b3.z * s.z + b3.w * s.w;

    #pragma unroll
    for (int sh = 1; sh < 16; sh <<= 1) {
        v0 += __shfl_xor(v0, sh);
        v1 += __shfl_xor(v1, sh);
        v2 += __shfl_xor(v2, sh);
        v3 += __shfl_xor(v3, sh);
    }

    if (c == 0) {
        const int rbase = t >> 4;   // 0..15
        float* o = out + (size_t)recv * D;
        atomicAdd(o + 0 * 16 + rbase, v0);
        atomicAdd(o + 1 * 16 + rbase, v1);
        atomicAdd(o + 2 * 16 + rbase, v2);
        atomicAdd(o + 3 * 16 + rbase, v3);
    }
}

extern "C" void kernel_launch(void* const* d_in, const int* in_sizes, int n_in,
                              void* d_out, int out_size, void* d_ws, size_t ws_size,
                              hipStream_t stream) {
    const float* atom = (const float*)d_in[0];   // (N_ATOMS, 64) f32
    const float* bond = (const float*)d_in[1];   // (N_EDGES, 64, 64) f32
    const int*   conn = (const int*)d_in[2];     // (N_EDGES, 2) i32 [recv, send]
    float* out = (float*)d_out;                  // (N_ATOMS, 64) f32

    const int edges = in_sizes[2] / 2;
    const int n4 = out_size / 4;                 // out_size divisible by 4 (D=64)

    zero_out_kernel<<<(n4 + 255) / 256, 256, 0, stream>>>(out, n4);
    msg_kernel<<<edges, 256, 0, stream>>>(atom, bond, conn, out);
}